// Round 1
// baseline (65.043 us; speedup 1.0000x reference)
//
#include <hip/hip_runtime.h>
#include <hip/hip_bf16.h>

typedef __attribute__((ext_vector_type(8))) short short8;
typedef __attribute__((ext_vector_type(4))) float f32x4;

#define ALPHA 0.2f
#define NEG_INF -9e15f
#define OUT_ROWS 126

__device__ __forceinline__ unsigned short f2bf(float x) {
    union { float f; unsigned int u; } v; v.f = x;
    unsigned int r = v.u + 0x7FFFu + ((v.u >> 16) & 1u);
    return (unsigned short)(r >> 16);
}

// One block: 126 output rows of one batch. Computes Wh for rows
// [row_start-1, row_start+126] (mod N) via bf16 MFMA, then windowed
// attention + combine, all fused in LDS.
__global__ __launch_bounds__(256, 2)
void gat_fused(const float* __restrict__ h, const int* __restrict__ opm,
               const float* __restrict__ W, const float* __restrict__ a,
               float* __restrict__ out, int N) {
    // [0,32768): h tile bf16 swizzled; [32768,65536): W^T bf16 swizzled.
    // After GEMM the whole 64KB becomes Wh f32 swizzled.
    __shared__ __align__(16) char smem[65536];
    __shared__ float a_s[256];
    __shared__ float wh1_s[128];
    __shared__ float wh2_s[128];
    __shared__ float att_s[128][4];

    const int t = threadIdx.x;
    const int b = blockIdx.y;
    const int row_start = blockIdx.x * OUT_ROWS;
    const int out_rows = min(OUT_ROWS, N - row_start);
    const float* hB = h + (size_t)b * N * 128;
    float* outB = out + (size_t)b * N * 128;

    a_s[t] = a[t];

    // ---- stage W^T (bf16, swizzled) ----
    #pragma unroll
    for (int i = 0; i < 16; ++i) {
        int idx4 = t + i * 256;                 // 4096 float4s of W
        int k = idx4 >> 5;                      // F_in row
        int n4 = (idx4 & 31) << 2;              // F_out col base
        float4 w4 = *(const float4*)(W + (k << 7) + n4);
        unsigned short bf[4] = { f2bf(w4.x), f2bf(w4.y), f2bf(w4.z), f2bf(w4.w) };
        #pragma unroll
        for (int j = 0; j < 4; ++j) {
            int jj = j ^ (t & 3);               // spread bank accesses
            int n = n4 + jj;
            *(unsigned short*)(smem + 32768 + n * 256 + ((k * 2) ^ ((n & 7) << 4))) = bf[jj];
        }
    }
    // ---- stage h tile (bf16, swizzled); rows wrap mod N (handles roll) ----
    #pragma unroll
    for (int i = 0; i < 16; ++i) {
        int idx4 = t + i * 256;
        int r = idx4 >> 5;
        int c = (idx4 & 31) << 2;
        int g = row_start - 1 + r;
        if (g < 0) g += N;
        if (g >= N) g -= N;
        float4 h4 = *(const float4*)(hB + (size_t)g * 128 + c);
        ushort4 p = make_ushort4(f2bf(h4.x), f2bf(h4.y), f2bf(h4.z), f2bf(h4.w));
        *(ushort4*)(smem + r * 256 + ((c * 2) ^ ((r & 7) << 4))) = p;
    }
    __syncthreads();

    // ---- GEMM: Wh[128][128] = hTile @ W, bf16 MFMA 16x16x32 ----
    const int lane = t & 63;
    const int wave = t >> 6;
    const int wr = (wave >> 1) << 6;            // 2x2 waves of 64x64
    const int wc = (wave & 1) << 6;
    const int l15 = lane & 15;
    const int lg = (lane >> 4) & 3;

    f32x4 acc[4][4];
    #pragma unroll
    for (int mi = 0; mi < 4; ++mi)
        #pragma unroll
        for (int ni = 0; ni < 4; ++ni)
            acc[mi][ni] = (f32x4){0.f, 0.f, 0.f, 0.f};

    #pragma unroll
    for (int kk = 0; kk < 4; ++kk) {
        int kbyte = (kk << 6) + (lg << 4);      // byte offset along K (8 bf16)
        short8 af[4], bfr[4];
        #pragma unroll
        for (int mi = 0; mi < 4; ++mi) {
            int m = wr + (mi << 4) + l15;
            af[mi] = *(const short8*)(smem + m * 256 + (kbyte ^ ((m & 7) << 4)));
        }
        #pragma unroll
        for (int ni = 0; ni < 4; ++ni) {
            int n = wc + (ni << 4) + l15;
            bfr[ni] = *(const short8*)(smem + 32768 + n * 256 + (kbyte ^ ((n & 7) << 4)));
        }
        #pragma unroll
        for (int mi = 0; mi < 4; ++mi)
            #pragma unroll
            for (int ni = 0; ni < 4; ++ni)
                acc[mi][ni] = __builtin_amdgcn_mfma_f32_16x16x32_bf16(
                    af[mi], bfr[ni], acc[mi][ni], 0, 0, 0);
    }
    __syncthreads();

    // ---- spill Wh to LDS as f32 (swizzled), overwriting staging buffers ----
    // C/D layout: col = lane&15, row = (lane>>4)*4 + reg  [HW-verified]
    #pragma unroll
    for (int mi = 0; mi < 4; ++mi) {
        #pragma unroll
        for (int ni = 0; ni < 4; ++ni) {
            int col = wc + (ni << 4) + l15;
            #pragma unroll
            for (int j = 0; j < 4; ++j) {
                int row = wr + (mi << 4) + (lg << 2) + j;
                *(float*)(smem + row * 512 + ((col * 4) ^ ((row & 7) << 4))) = acc[mi][ni][j];
            }
        }
    }
    __syncthreads();

    // ---- Wh1 = Wh.a1, Wh2 = Wh.a2 (2 threads per row) ----
    {
        int r = t >> 1;
        int cb = (t & 1) << 6;
        float s1 = 0.f, s2 = 0.f;
        #pragma unroll
        for (int i = 0; i < 16; ++i) {
            int c = cb + (i << 2);
            f32x4 w4 = *(const f32x4*)(smem + r * 512 + ((c * 4) ^ ((r & 7) << 4)));
            s1 += w4[0] * a_s[c] + w4[1] * a_s[c + 1] + w4[2] * a_s[c + 2] + w4[3] * a_s[c + 3];
            s2 += w4[0] * a_s[128 + c] + w4[1] * a_s[129 + c] + w4[2] * a_s[130 + c] + w4[3] * a_s[131 + c];
        }
        s1 += __shfl_xor(s1, 1);
        s2 += __shfl_xor(s2, 1);
        if ((t & 1) == 0) { wh1_s[r] = s1; wh2_s[r] = s2; }
    }
    __syncthreads();

    // ---- attention coefficients per output row ----
    if (t < 128) {
        int r = t;
        if (r >= 1 && r <= out_rows) {
            int g = row_start + r - 1;
            const int* mr = opm + ((size_t)b * N + g) * 3;
            float w1 = wh1_s[r];
            float e0 = w1 + wh2_s[r - 1];   // k=0: prev
            float e1 = w1 + wh2_s[r];       // k=1: self
            float e2 = w1 + wh2_s[r + 1];   // k=2: next
            e0 = e0 > 0.f ? e0 : ALPHA * e0;
            e1 = e1 > 0.f ? e1 : ALPHA * e1;
            e2 = e2 > 0.f ? e2 : ALPHA * e2;
            if (mr[0] > 0) e0 = NEG_INF;
            if (mr[1] > 0) e1 = NEG_INF;
            if (mr[2] > 0) e2 = NEG_INF;
            float m = fmaxf(e0, fmaxf(e1, e2));
            float x0 = expf(e0 - m), x1 = expf(e1 - m), x2 = expf(e2 - m);
            float inv = 1.f / (x0 + x1 + x2);
            att_s[r][0] = x0 * inv;
            att_s[r][1] = x1 * inv;
            att_s[r][2] = x2 * inv;
        }
    }
    __syncthreads();

    // ---- combine: out[n] = att0*Wh[n-1] + att1*Wh[n] + att2*Wh[n+1] ----
    for (int it = 0; it < 16; ++it) {
        int r = 1 + (wave << 1) + ((lane >> 5) & 1) + (it << 3);
        if (r > out_rows) continue;
        int c = (lane & 31) << 2;
        float a0 = att_s[r][0], a1 = att_s[r][1], a2 = att_s[r][2];
        f32x4 wm = *(const f32x4*)(smem + (r - 1) * 512 + ((c * 4) ^ (((r - 1) & 7) << 4)));
        f32x4 w0 = *(const f32x4*)(smem + r * 512 + ((c * 4) ^ ((r & 7) << 4)));
        f32x4 wp = *(const f32x4*)(smem + (r + 1) * 512 + ((c * 4) ^ (((r + 1) & 7) << 4)));
        f32x4 res;
        #pragma unroll
        for (int j = 0; j < 4; ++j)
            res[j] = a0 * wm[j] + a1 * w0[j] + a2 * wp[j];
        int g = row_start + r - 1;
        *(f32x4*)(outB + (size_t)g * 128 + c) = res;
    }
}

extern "C" void kernel_launch(void* const* d_in, const int* in_sizes, int n_in,
                              void* d_out, int out_size, void* d_ws, size_t ws_size,
                              hipStream_t stream) {
    const float* h   = (const float*)d_in[0];
    const int*   opm = (const int*)d_in[1];
    const float* W   = (const float*)d_in[2];
    const float* a   = (const float*)d_in[3];
    float* out = (float*)d_out;
    const int N = 65536;
    const int B = 4;
    dim3 grid((N + OUT_ROWS - 1) / OUT_ROWS, B);
    gat_fused<<<grid, 256, 0, stream>>>(h, opm, W, a, out, N);
}